// Round 5
// baseline (109.374 us; speedup 1.0000x reference)
//
#include <hip/hip_runtime.h>
#include <math.h>

// Problem constants (fixed by setup_inputs shapes).
constexpr int Bc  = 8;
constexpr int Tc  = 4096;
constexpr int HLc = 8;
constexpr int Dc  = 128;
constexpr int Sc  = 4096;
constexpr int TBc = 64;   // Tb = T / bs
constexpr int BSc = 64;   // sparse_block_size

// Output offsets (float elements) in concatenated d_out, in return order.
constexpr long long O_KC   = 0LL;
constexpr long long O_VC   = 33554432LL;   // + B*T*Hl*D
constexpr long long O_VNT  = 67108864LL;   // + B*T*Hl*D
constexpr long long O_KSUM = 67371008LL;   // + B*T*Hl
constexpr long long O_CNT  = 67895296LL;   // + B*Tb*Hl*D
constexpr long long O_VNB  = 67895808LL;   // + B*Tb
constexpr long long O_PRE  = 67899904LL;   // + B*Tb*Hl

typedef float f4 __attribute__((ext_vector_type(4)));

__device__ inline f4 ntload4(const float* p) {
    return __builtin_nontemporal_load(reinterpret_cast<const f4*>(p));
}
__device__ inline void ntstore4(float* p, f4 v) {
    __builtin_nontemporal_store(v, reinterpret_cast<f4*>(p));
}

// Single fused kernel. One WG per (b, tb): owns a contiguous 64x(Hl*D)
// = 256 KB region of each cache. Prep (inverse map / count / maxpos) is
// computed per-WG from pos[] (16 KB, L2-resident after first WG).
// Streaming is two separated passes (K then V), each: 16 NT loads issued
// back-to-back, then 16 NT stores — maximizes outstanding VMEM ops.
__global__ __launch_bounds__(1024) void k_main(
    const float* __restrict__ kc_old, const float* __restrict__ vc_old,
    const float* __restrict__ vnt_old, const float* __restrict__ ksum_old,
    const int* __restrict__ kcnt_old, const float* __restrict__ vnb_old,
    const float* __restrict__ kb, const float* __restrict__ vb,
    const float* __restrict__ vnorm, const int* __restrict__ pos,
    float* __restrict__ out)
{
    const int wg  = blockIdx.x;
    const int tb  = wg % TBc;
    const int b   = wg / TBc;
    const int tid = threadIdx.x;
    const int q   = tid >> 8;     // t-phase 0..3 (uniform per wave)
    const int p   = tid & 255;    // float4 slot within the 1024-float row

    __shared__ int   inv_l[BSc];
    __shared__ int   cnt_l;
    __shared__ int   maxp_l;
    __shared__ f4    red4[1024];
    __shared__ float vn_l[BSc * HLc];

    if (tid < BSc) inv_l[tid] = -1;
    if (tid == 0) { cnt_l = 0; maxp_l = -1; }
    __syncthreads();

    // Per-WG prep scan over pos[] (uniform across WGs -> cache-resident).
    {
        const int base = tb * BSc;
        int lmax = -1;
        #pragma unroll
        for (int j = 0; j < Sc / 1024; ++j) {
            const int s  = tid + j * 1024;
            const int pp = pos[s];
            lmax = max(lmax, pp);
            if (pp >= base && pp < base + BSc) {
                atomicMax(&inv_l[pp - base], s);   // last-write-wins on dups
                atomicAdd(&cnt_l, 1);
            }
        }
        if (wg == 0) {   // only WG 0 needs max(pos) for prefill_len
            #pragma unroll
            for (int off = 32; off >= 1; off >>= 1)
                lmax = max(lmax, __shfl_xor(lmax, off));
            if ((tid & 63) == 0) atomicMax(&maxp_l, lmax);
        }
    }
    __syncthreads();

    const long long ROW     = (long long)HLc * Dc;              // 1024
    const long long dstBase = ((long long)(b * Tc + tb * BSc)) * ROW;
    const long long srcBase = ((long long)b * Sc) * ROW;

    // Per-row source offsets + coverage (wave-uniform inv_l reads).
    long long soff[16], doff[16];
    bool cov[16];
    #pragma unroll
    for (int i = 0; i < 16; ++i) {
        const int r = i * 4 + q;                  // row in block 0..63
        const int s = inv_l[r];
        cov[i]  = (s >= 0);
        doff[i] = dstBase + (long long)r * ROW + p * 4;
        soff[i] = cov[i] ? (srcBase + (long long)s * ROW + p * 4) : doff[i];
    }

    // ---- K pass: 16 loads in flight, then sum+store drain ----
    f4 kreg[16];
    #pragma unroll
    for (int i = 0; i < 16; ++i)
        kreg[i] = ntload4((cov[i] ? kb : kc_old) + soff[i]);
    f4 ksum = (f4){0.f, 0.f, 0.f, 0.f};
    #pragma unroll
    for (int i = 0; i < 16; ++i) {
        if (cov[i]) ksum += kreg[i];
        ntstore4(out + O_KC + doff[i], kreg[i]);
    }

    // ---- V pass ----
    f4 vreg[16];
    #pragma unroll
    for (int i = 0; i < 16; ++i)
        vreg[i] = ntload4((cov[i] ? vb : vc_old) + soff[i]);
    #pragma unroll
    for (int i = 0; i < 16; ++i)
        ntstore4(out + O_VC + doff[i], vreg[i]);

    // v_norm_tok: 512 contiguous floats per WG, fully coalesced; stash
    // incoming values in LDS for the per-h max.
    if (tid < BSc * HLc) {
        const int tl = tid >> 3, h = tid & 7;
        const int s  = inv_l[tl];
        const long long di = ((long long)(b * Tc + tb * BSc + tl)) * HLc + h;
        float vn, vm;
        if (s >= 0) {
            vn = vnorm[(((long long)b * Sc) + s) * HLc + h];
            vm = vn;
        } else {
            vn = vnt_old[di];
            vm = -INFINITY;
        }
        out[O_VNT + di] = vn;
        vn_l[tid] = vm;
    }
    red4[tid] = ksum;
    __syncthreads();

    // k_sum_blk: reduce 4 t-phase partials per slot, add old, write float4.
    if (q == 0) {
        f4 a = red4[p], c = red4[256 + p], d = red4[512 + p],
           e = red4[768 + p];
        const long long o = ((long long)(b * TBc + tb)) * ROW + p * 4;
        f4 old = *reinterpret_cast<const f4*>(ksum_old + o);
        f4 tot = old + a + c + d + e;
        ntstore4(out + O_KSUM + o, tot);
    }

    // v_norm_blk: per-h running max.
    if (tid < HLc) {
        float m = vnb_old[((long long)(b * TBc + tb)) * HLc + tid];
        #pragma unroll
        for (int t = 0; t < BSc; ++t) m = fmaxf(m, vn_l[t * HLc + tid]);
        out[O_VNB + ((long long)(b * TBc + tb)) * HLc + tid] = m;
    }

    // counts + prefill_len (d_out read back as float32: write values).
    if (tid == 0) {
        out[O_CNT + b * TBc + tb] = (float)(kcnt_old[b * TBc + tb] + cnt_l);
        if (wg == 0) out[O_PRE] = (float)(maxp_l + 1);
    }
}

extern "C" void kernel_launch(void* const* d_in, const int* in_sizes, int n_in,
                              void* d_out, int out_size, void* d_ws, size_t ws_size,
                              hipStream_t stream) {
    const float* kc_old   = (const float*)d_in[0];
    const float* vc_old   = (const float*)d_in[1];
    const float* vnt_old  = (const float*)d_in[2];
    const float* ksum_old = (const float*)d_in[3];
    const int*   kcnt_old = (const int*)d_in[4];
    const float* vnb_old  = (const float*)d_in[5];
    const int*   pos      = (const int*)d_in[6];
    const float* kb       = (const float*)d_in[7];
    const float* vb       = (const float*)d_in[8];
    const float* vnorm    = (const float*)d_in[9];
    float* out = (float*)d_out;

    k_main<<<Bc * TBc, 1024, 0, stream>>>(kc_old, vc_old, vnt_old, ksum_old,
                                          kcnt_old, vnb_old, kb, vb, vnorm,
                                          pos, out);
}

// Round 6
// 106.163 us; speedup vs baseline: 1.0302x; 1.0302x over previous
//
#include <hip/hip_runtime.h>
#include <math.h>

// Problem constants (fixed by setup_inputs shapes).
constexpr int Bc  = 8;
constexpr int Tc  = 4096;
constexpr int HLc = 8;
constexpr int Dc  = 128;
constexpr int Sc  = 4096;
constexpr int TBc = 64;   // Tb = T / bs
constexpr int BSc = 64;   // sparse_block_size

// Output offsets (float elements) in concatenated d_out, in return order.
constexpr long long O_KC   = 0LL;
constexpr long long O_VC   = 33554432LL;   // + B*T*Hl*D
constexpr long long O_VNT  = 67108864LL;   // + B*T*Hl*D
constexpr long long O_KSUM = 67371008LL;   // + B*T*Hl
constexpr long long O_CNT  = 67895296LL;   // + B*Tb*Hl*D
constexpr long long O_VNB  = 67895808LL;   // + B*Tb
constexpr long long O_PRE  = 67899904LL;   // + B*Tb*Hl

typedef float f4 __attribute__((ext_vector_type(4)));

__device__ inline f4 ntload4(const float* p) {
    return __builtin_nontemporal_load(reinterpret_cast<const f4*>(p));
}
__device__ inline void ntstore4(float* p, f4 v) {
    __builtin_nontemporal_store(v, reinterpret_cast<f4*>(p));
}

// Single fused kernel. One WG per (b, tb): owns a contiguous 64x(Hl*D)
// = 256 KB region of each cache. Prep (inverse map / count / maxpos) is
// computed per-WG from pos[] (16 KB, L2-resident after first WG).
// All offsets are 32-bit (max index ~67.9M < 2^31): SGPR-base + voffset
// addressing, low VGPR count, 2 WGs/CU residency.
__global__ __launch_bounds__(1024) void k_main(
    const float* __restrict__ kc_old, const float* __restrict__ vc_old,
    const float* __restrict__ vnt_old, const float* __restrict__ ksum_old,
    const int* __restrict__ kcnt_old, const float* __restrict__ vnb_old,
    const float* __restrict__ kb, const float* __restrict__ vb,
    const float* __restrict__ vnorm, const int* __restrict__ pos,
    float* __restrict__ out)
{
    const int wg  = blockIdx.x;
    const int tb  = wg % TBc;
    const int b   = wg / TBc;
    const int tid = threadIdx.x;
    const int q   = tid >> 8;     // t-phase 0..3 (uniform per 64-lane wave)
    const int p   = tid & 255;    // float4 slot within the 1024-float row

    __shared__ int   inv_l[BSc];
    __shared__ int   cnt_l;
    __shared__ int   maxp_l;
    __shared__ f4    red4[1024];
    __shared__ float vn_l[BSc * HLc];

    if (tid < BSc) inv_l[tid] = -1;
    if (tid == 0) { cnt_l = 0; maxp_l = -1; }
    __syncthreads();

    // Per-WG prep scan over pos[] (uniform across WGs -> cache-resident).
    {
        const int base = tb * BSc;
        int lmax = -1;
        #pragma unroll
        for (int j = 0; j < Sc / 1024; ++j) {
            const int s  = tid + j * 1024;
            const int pp = pos[s];
            lmax = max(lmax, pp);
            if (pp >= base && pp < base + BSc) {
                atomicMax(&inv_l[pp - base], s);   // last-write-wins on dups
                atomicAdd(&cnt_l, 1);
            }
        }
        if (wg == 0) {   // only WG 0 needs max(pos) for prefill_len
            #pragma unroll
            for (int off = 32; off >= 1; off >>= 1)
                lmax = max(lmax, __shfl_xor(lmax, off));
            if ((tid & 63) == 0) atomicMax(&maxp_l, lmax);
        }
    }
    __syncthreads();

    constexpr int ROW = HLc * Dc;                    // 1024
    const int dstBase = (b * Tc + tb * BSc) * ROW;   // < 2^25 * 8, fits int
    const int srcBase = b * Sc * ROW;

    float* const okc = out + O_KC;
    float* const ovc = out + O_VC;

    f4 ksum = (f4){0.f, 0.f, 0.f, 0.f};
    #pragma unroll
    for (int i = 0; i < 16; ++i) {
        const int r = i * 4 + q;                         // row in block 0..63
        // inv_l[r] is wave-uniform: make it scalar -> s_cmp branch + SGPR base.
        const int s = __builtin_amdgcn_readfirstlane(inv_l[r]);
        const int dst = dstBase + r * ROW + p * 4;
        f4 kv, vv;
        if (s >= 0) {
            const int src = srcBase + s * ROW + p * 4;
            kv = ntload4(kb + src);
            vv = ntload4(vb + src);
            ksum += kv;
        } else {
            kv = ntload4(kc_old + dst);
            vv = ntload4(vc_old + dst);
        }
        ntstore4(okc + dst, kv);
        ntstore4(ovc + dst, vv);
    }

    // v_norm_tok: 512 contiguous floats per WG, fully coalesced; stash
    // incoming values in LDS for the per-h max.
    if (tid < BSc * HLc) {
        const int tl = tid >> 3, h = tid & 7;
        const int s  = inv_l[tl];
        const int di = (b * Tc + tb * BSc + tl) * HLc + h;
        float vn, vm;
        if (s >= 0) {
            vn = vnorm[(b * Sc + s) * HLc + h];
            vm = vn;
        } else {
            vn = vnt_old[di];
            vm = -INFINITY;
        }
        out[O_VNT + di] = vn;
        vn_l[tid] = vm;
    }
    red4[tid] = ksum;
    __syncthreads();

    // k_sum_blk: reduce 4 t-phase partials per slot, add old, write float4.
    if (q == 0) {
        f4 a = red4[p], c = red4[256 + p], d = red4[512 + p],
           e = red4[768 + p];
        const int o = (b * TBc + tb) * ROW + p * 4;
        f4 old = *reinterpret_cast<const f4*>(ksum_old + o);
        f4 tot = old + a + c + d + e;
        ntstore4(out + O_KSUM + o, tot);
    }

    // v_norm_blk: per-h running max.
    if (tid < HLc) {
        float m = vnb_old[(b * TBc + tb) * HLc + tid];
        #pragma unroll
        for (int t = 0; t < BSc; ++t) m = fmaxf(m, vn_l[t * HLc + tid]);
        out[O_VNB + (b * TBc + tb) * HLc + tid] = m;
    }

    // counts + prefill_len (d_out read back as float32: write values).
    if (tid == 0) {
        out[O_CNT + b * TBc + tb] = (float)(kcnt_old[b * TBc + tb] + cnt_l);
        if (wg == 0) out[O_PRE] = (float)(maxp_l + 1);
    }
}

extern "C" void kernel_launch(void* const* d_in, const int* in_sizes, int n_in,
                              void* d_out, int out_size, void* d_ws, size_t ws_size,
                              hipStream_t stream) {
    const float* kc_old   = (const float*)d_in[0];
    const float* vc_old   = (const float*)d_in[1];
    const float* vnt_old  = (const float*)d_in[2];
    const float* ksum_old = (const float*)d_in[3];
    const int*   kcnt_old = (const int*)d_in[4];
    const float* vnb_old  = (const float*)d_in[5];
    const int*   pos      = (const int*)d_in[6];
    const float* kb       = (const float*)d_in[7];
    const float* vb       = (const float*)d_in[8];
    const float* vnorm    = (const float*)d_in[9];
    float* out = (float*)d_out;

    k_main<<<Bc * TBc, 1024, 0, stream>>>(kc_old, vc_old, vnt_old, ksum_old,
                                          kcnt_old, vnb_old, kb, vb, vnorm,
                                          pos, out);
}